// Round 1
// baseline (170.287 us; speedup 1.0000x reference)
//
#include <hip/hip_runtime.h>

// InfoCNECauchy: loss = mean_r log(sum_{j!=r} sim[r,j]) - mean_r log(sim[r, r^4096])
// sim = t^2/(d2+t^2), d2 = ||f_r||^2 + ||f_c||^2 - 2<f_r,f_c>, t=0.07
//
// R6: port the GEMM to the 256^2 8-phase schedule (T2+T3+T4+T5 from the CDNA4
// guide; 2-phase 128^2 structure ceiling ~36% MFMA, 8-phase 256^2 measured
// 62%+). Kept verbatim from R5 (all harness-verified): packed XOR LDS layout
// (0 bank conflicts), fragment-read swizzle, Cauchy epilogue math, prep/final.
// New: BM=BN=BK-tiling 256x256x64, 512 thr / 8 waves (2Mx4N), per-wave 128x64
// output. LDS 128 KiB = [op][dbuf][Mhalf][ksub] x (128x32 packed). Per phase:
// {ds_read frags || issue 1 half-tile global_load_lds -> raw s_barrier ->
// setprio(1) 16xMFMA setprio(0)} ; counted s_waitcnt vmcnt(4) ONLY at phases
// 4 and 8 (loads stay in flight across barriers; __syncthreads would emit
// vmcnt(0) and re-create the m97 drain stall). Stage targets chosen so every
// LDS overwrite is >=1 barrier after the region's last ds_read. Last iter
// peeled (vmcnt(0)). Grid = 528 upper-tri tiles, banded 66-per-XCD exactly.

#define N2 8192
#define DIM 512
#define TNT 32                 /* 8192/256 tiles per dim */
#define NTILES 528             /* TNT*(TNT+1)/2 */
#define T2 0.0049f

typedef float floatx4 __attribute__((ext_vector_type(4)));
typedef __bf16 bf16x8 __attribute__((ext_vector_type(8)));
typedef __bf16 bf16x4 __attribute__((ext_vector_type(4)));

__device__ __forceinline__ void load_to_lds16(const void* g, void* l) {
  auto gp = (const __attribute__((address_space(1))) void*)(reinterpret_cast<uintptr_t>(g));
  auto lp = (__attribute__((address_space(3))) void*)(reinterpret_cast<uintptr_t>(l));
  __builtin_amdgcn_global_load_lds(gp, lp, 16, 0, 0);
}

// ---- prep: fp32 -> bf16 + row norms + zero rowsum ------------------------
__global__ __launch_bounds__(256) void prep_kernel(const float* __restrict__ f,
                                                   __bf16* __restrict__ fbf,
                                                   float* __restrict__ sq,
                                                   float* __restrict__ rowsum) {
  const int t = threadIdx.x;
  if (t < 2) rowsum[blockIdx.x * 2 + t] = 0.f;
  const int row = blockIdx.x * 2 + (t >> 7);
  const int ci = (t & 127) * 4;
  const float4 v = *(const float4*)(f + (size_t)row * DIM + ci);
  bf16x4 b;
  b[0] = (__bf16)v.x; b[1] = (__bf16)v.y; b[2] = (__bf16)v.z; b[3] = (__bf16)v.w;
  *(bf16x4*)(fbf + (size_t)row * DIM + ci) = b;
  float s = v.x * v.x + v.y * v.y + v.z * v.z + v.w * v.w;
#pragma unroll
  for (int off = 1; off < 64; off <<= 1) s += __shfl_xor(s, off, 64);
  __shared__ float red[4];
  if ((t & 63) == 0) red[t >> 6] = s;
  __syncthreads();
  if ((t & 127) == 0) sq[row] = red[t >> 6] + red[(t >> 6) + 1];
}

// ---- fused 256^2 8-phase GEMM (upper triangle) + Cauchy epilogue ---------
// LDS region: op in {0=A,1=B}, d = K-tile parity (dbuf), h = M/N half,
// ks = 32-col K-subtile. Each region: 128 rows x 32 cols packed as 64
// rowpairs x 8 16B-chunk slots, chunk slot u' = u ^ (rp&7),
// u = (row&1)*4 + chunk.  (verified layout from R2/R5, 0 bank conflicts)
#define LDSREG(op, d, h, ks) (((((op)*2 + (d))*2 + (h))*2 + (ks)) * 4096)
#define SB __builtin_amdgcn_sched_barrier(0)
#define PHASE_MID do { SB; __builtin_amdgcn_s_barrier(); SB; } while (0)
#define PHASE_END do { SB; __builtin_amdgcn_s_barrier(); SB; } while (0)
#define VM4 asm volatile("s_waitcnt vmcnt(4)" ::: "memory")
#define VM0 asm volatile("s_waitcnt vmcnt(0)" ::: "memory")

__global__ __launch_bounds__(512, 2) void gemm_kernel(const __bf16* __restrict__ fbf,
                                                      const float* __restrict__ sq,
                                                      float* __restrict__ rowsum,
                                                      float* __restrict__ spart) {
  __shared__ __bf16 lds[16 * 4096];  // 128 KiB

  // Banded tile decode: 16 bands of 2 tile-rows; XCD x owns bands x and 15-x
  // -> exactly 66 tiles per XCD (63-4x + 3+4x), bx-major within band.
  int by, bx;
  {
    const int x = blockIdx.x & 7;
    int kk = blockIdx.x >> 3;           // 0..65
    int band = x;
    const int n1 = 63 - 4 * x;          // tiles in band x
    if (kk >= n1) { kk -= n1; band = 15 - x; }
    const int by0 = band * 2;
    int bxx = by0;
    int cnt;
    while (kk >= (cnt = min(2, bxx - by0 + 1))) { kk -= cnt; ++bxx; }
    by = by0 + kk;
    bx = bxx;
  }
  const int brow = by * 256;
  const int bcol = bx * 256;
  const bool diag = (by == bx);
  const bool ptile = (bx == by + 16);   // only these tiles contain (r, r^4096)

  const int t = threadIdx.x;
  const int lane = t & 63;
  const int w = t >> 6;                 // wave 0..7
  const int wr = w >> 2;                // 0..1: M 64-row sub within quadrant
  const int wc = w & 3;                 // 0..3: N 32-col sub within quadrant
  const int q4 = lane >> 4;
  const int lc = lane & 15;
  const int rhalf = lc >> 1;
  const int up = (((lc & 1) * 4) + q4) ^ rhalf;  // fragment-read swizzle (verified)

  // staging lane -> (row, 16B chunk) under XOR swizzle (verified map)
  const int rp = t >> 3;
  const int uu = (t & 7) ^ (rp & 7);
  const int grow = rp * 2 + (uu >> 2);  // 0..127
  const int gofs = (uu & 3) * 8;        // bf16 elements

  floatx4 acc[4][4][2] = {};            // [quadrant qm*2+qn][mf][nf]
  bf16x8 af[4][2];                      // A frags, live across a quadrant-row pair
  bf16x8 bv0[2][2], bv1[2][2];          // B frags for qn=0 / qn=1, live across d-half

#define STAGE(kt, opB, h) do {                                                \
    const int kt_ = (kt);                                                     \
    const int dd_ = kt_ & 1;                                                  \
    const size_t srow_ = (size_t)(((opB) ? bcol : brow) + (h)*128 + grow);    \
    load_to_lds16(fbf + srow_ * DIM + kt_ * 64 + gofs,                        \
                  &lds[LDSREG((opB), dd_, (h), 0) + t * 8]);                  \
    load_to_lds16(fbf + srow_ * DIM + kt_ * 64 + 32 + gofs,                   \
                  &lds[LDSREG((opB), dd_, (h), 1) + t * 8]);                  \
  } while (0)

#define READ_A(d, qm) do {                                                    \
    _Pragma("unroll") for (int mf = 0; mf < 4; ++mf)                          \
      _Pragma("unroll") for (int ks = 0; ks < 2; ++ks)                        \
        af[mf][ks] = *(const bf16x8*)&lds[LDSREG(0, d, qm, ks) +              \
            (wr * 32 + mf * 8 + rhalf) * 64 + up * 8];                        \
  } while (0)

#define READ_B(d, qn, BV) do {                                                \
    _Pragma("unroll") for (int nf = 0; nf < 2; ++nf)                          \
      _Pragma("unroll") for (int ks = 0; ks < 2; ++ks)                        \
        BV[nf][ks] = *(const bf16x8*)&lds[LDSREG(1, d, qn, ks) +              \
            (wc * 16 + nf * 8 + rhalf) * 64 + up * 8];                        \
  } while (0)

#define MFMAS(qid, BV) do {                                                   \
    __builtin_amdgcn_s_setprio(1);                                           \
    _Pragma("unroll") for (int mf = 0; mf < 4; ++mf)                          \
      _Pragma("unroll") for (int nf = 0; nf < 2; ++nf)                        \
        _Pragma("unroll") for (int ks = 0; ks < 2; ++ks)                      \
          acc[qid][mf][nf] = __builtin_amdgcn_mfma_f32_16x16x32_bf16(         \
              af[mf][ks], BV[nf][ks], acc[qid][mf][nf], 0, 0, 0);             \
    __builtin_amdgcn_s_setprio(0);                                            \
  } while (0)

  // ---- prologue: kt0 complete + kt1.{A0,B0} in flight ----
  STAGE(0, 0, 0); STAGE(0, 0, 1); STAGE(0, 1, 0); STAGE(0, 1, 1);
  STAGE(1, 0, 0); STAGE(1, 1, 0);
  VM4;                                  // oldest 8 loads = all of kt0 landed
  PHASE_MID;

  // ---- main loop: iterations over K-tile pairs (kt = k2, k2+1) ----
#pragma unroll 1
  for (int k2 = 0; k2 < 6; k2 += 2) {
    // d=0 phases (kt = k2), quadrants (qm,qn)=(0,0),(0,1),(1,0),(1,1)
    READ_A(0, 0); READ_B(0, 0, bv0); STAGE(k2 + 1, 0, 1);
    PHASE_MID; MFMAS(0, bv0); PHASE_END;
    READ_B(0, 1, bv1);                STAGE(k2 + 1, 1, 1);
    PHASE_MID; MFMAS(1, bv1); PHASE_END;
    READ_A(0, 1);                     STAGE(k2 + 2, 0, 0);
    PHASE_MID; MFMAS(2, bv0); PHASE_END;
                                      STAGE(k2 + 2, 1, 0);
    PHASE_MID; MFMAS(3, bv1); VM4; PHASE_END;   // kt k2+1 fully landed
    // d=1 phases (kt = k2+1)
    READ_A(1, 0); READ_B(1, 0, bv0);  STAGE(k2 + 2, 0, 1);
    PHASE_MID; MFMAS(0, bv0); PHASE_END;
    READ_B(1, 1, bv1);                STAGE(k2 + 2, 1, 1);
    PHASE_MID; MFMAS(1, bv1); PHASE_END;
    READ_A(1, 1);                     STAGE(k2 + 3, 0, 0);
    PHASE_MID; MFMAS(2, bv0); PHASE_END;
                                      STAGE(k2 + 3, 1, 0);
    PHASE_MID; MFMAS(3, bv1); VM4; PHASE_END;   // kt k2+2 fully landed
  }

  // ---- peeled last iteration: kt 6,7 (finish kt7 staging, then drain) ----
  READ_A(0, 0); READ_B(0, 0, bv0); STAGE(7, 0, 1);
  PHASE_MID; MFMAS(0, bv0); PHASE_END;
  READ_B(0, 1, bv1);               STAGE(7, 1, 1);
  PHASE_MID; MFMAS(1, bv1); PHASE_END;
  READ_A(0, 1);
  PHASE_MID; MFMAS(2, bv0); PHASE_END;
  PHASE_MID; MFMAS(3, bv1); VM0; PHASE_END;     // all of kt7 landed
  READ_A(1, 0); READ_B(1, 0, bv0);
  PHASE_MID; MFMAS(0, bv0); PHASE_END;
  READ_B(1, 1, bv1);
  PHASE_MID; MFMAS(1, bv1); PHASE_END;
  READ_A(1, 1);
  PHASE_MID; MFMAS(2, bv0); PHASE_END;
  PHASE_MID; MFMAS(3, bv1); PHASE_END;

  asm volatile("" ::: "memory");  // keep epilogue loads from hoisting into the
                                  // counted-vmcnt region (would corrupt counts)

  // ---- epilogue. C/D layout: col = lane&15, row = (lane>>4)*4 + reg. ----
  // s = T2 * rcp(max(d2,0)+T2) = T2 * rcp(max(sr+sc+T2-2g, T2)); accumulate
  // rcp results, scale by T2 once at the atomics.
  float sqc[2][2];
#pragma unroll
  for (int qn = 0; qn < 2; ++qn)
#pragma unroll
    for (int nf = 0; nf < 2; ++nf)
      sqc[qn][nf] = sq[bcol + qn * 128 + wc * 32 + nf * 16 + lc] + T2;

  float cs[2][2] = {{0.f, 0.f}, {0.f, 0.f}};

#pragma unroll
  for (int qm = 0; qm < 2; ++qm) {
#pragma unroll
    for (int mf = 0; mf < 4; ++mf) {
#pragma unroll
      for (int reg = 0; reg < 4; ++reg) {
        const int r = brow + qm * 128 + wr * 64 + mf * 16 + q4 * 4 + reg;
        const float sr = sq[r];
        const int pc = r ^ (N2 / 2);
        float rs = 0.f;
#pragma unroll
        for (int qn = 0; qn < 2; ++qn) {
#pragma unroll
          for (int nf = 0; nf < 2; ++nf) {
            const int c = bcol + qn * 128 + wc * 32 + nf * 16 + lc;
            const float g = acc[qm * 2 + qn][mf][nf][reg];
            const float u = __builtin_amdgcn_rcpf(fmaxf(sr + sqc[qn][nf] - 2.f * g, T2));
            if (c != r) rs += u;     // diagonal excluded exactly (diag tiles only)
            cs[qn][nf] += u;         // unused on diag tiles
            if (ptile && c == pc) { const float s = T2 * u; spart[r] = s; spart[pc] = s; }
          }
        }
#pragma unroll
        for (int off = 1; off < 16; off <<= 1) rs += __shfl_xor(rs, off, 64);
        if (lc == 0) atomicAdd(&rowsum[r], T2 * rs);
      }
    }
  }

  if (!diag) {
#pragma unroll
    for (int qn = 0; qn < 2; ++qn)
#pragma unroll
      for (int nf = 0; nf < 2; ++nf) {
        float v = cs[qn][nf];
        v += __shfl_xor(v, 16, 64);
        v += __shfl_xor(v, 32, 64);
        if (lane < 16) atomicAdd(&rowsum[bcol + qn * 128 + wc * 32 + nf * 16 + lane], T2 * v);
      }
  }
}

// ---- final scalar reduction ---------------------------------------------
__global__ __launch_bounds__(256) void final_kernel(const float* __restrict__ rowsum,
                                                    const float* __restrict__ spart,
                                                    float* __restrict__ out) {
  const int t = threadIdx.x;
  float a = 0.f;
  for (int r = t; r < N2; r += 256) a += logf(rowsum[r]) - logf(spart[r]);
#pragma unroll
  for (int off = 1; off < 64; off <<= 1) a += __shfl_xor(a, off, 64);
  __shared__ float red[4];
  if ((t & 63) == 0) red[t >> 6] = a;
  __syncthreads();
  if (t == 0) out[0] = (red[0] + red[1] + red[2] + red[3]) * (1.0f / (float)N2);
}

extern "C" void kernel_launch(void* const* d_in, const int* in_sizes, int n_in,
                              void* d_out, int out_size, void* d_ws, size_t ws_size,
                              hipStream_t stream) {
  const float* features = (const float*)d_in[0];
  float* out = (float*)d_out;

  char* ws = (char*)d_ws;
  __bf16* fbf = (__bf16*)ws;                                     // 8 MB
  float* sq = (float*)(ws + (size_t)N2 * DIM * sizeof(__bf16));  // 32 KB
  float* rowsum = sq + N2;                                       // 32 KB
  float* spart = rowsum + N2;                                    // 32 KB

  prep_kernel<<<N2 / 2, 256, 0, stream>>>(features, fbf, sq, rowsum);
  gemm_kernel<<<NTILES, 512, 0, stream>>>(fbf, sq, rowsum, spart);
  final_kernel<<<1, 256, 0, stream>>>(rowsum, spart, out);
}

// Round 2
// 151.861 us; speedup vs baseline: 1.1213x; 1.1213x over previous
//
#include <hip/hip_runtime.h>

// InfoCNECauchy: loss = mean_r log(sum_{j!=r} sim[r,j]) - mean_r log(sim[r, r^4096])
// sim = t^2/(d2+t^2), d2 = ||f_r||^2 + ||f_c||^2 - 2<f_r,f_c>, t=0.07
//
// R7: R5's proven gemm body (16x16x32, 4x4 accs, XOR-swizzled LDS, 0 bank
// conflicts, 72 us) with ONE change: tile->XCD map. R6 post-mortem showed the
// 256^2 8-phase port was latency-bound (1 blk/CU) and that R5 moves 532 MB of
// panels at 7.4 TB/s = L3-fabric class: row-banding leaves the B working set
// at ~8 MB/XCD (streams from L3 every pass). R7 maps 2048^2 SUPER-BLOCKS to
// XCDs: off-diag super = 2 MB A + 2 MB B = 4 MB = one XCD's L2, so after the
// first warm pass ~15/16 of panel reads are L2 hits. Partition (exactly 260
// blocks == x mod 8 per XCD, matching round-robin dispatch):
//   XCD 0..5 : off-diag supers (0,1),(0,2),(0,3),(1,2),(1,3),(2,3): 256 tiles
//              + 4 donated diag tiles each (last 24 of diag enumeration)
//   XCD 6    : diag tiles g=0..259    (super (0,0) + most of (1,1))
//   XCD 7    : diag tiles g=260..519  (rest of (1,1), (2,2), most of (3,3))

#define N2 8192
#define DIM 512
#define NT 64 /* 8192/128 tiles per dim */
#define NTILES (NT * (NT + 1) / 2)
#define T2 0.0049f

typedef float floatx4 __attribute__((ext_vector_type(4)));
typedef __bf16 bf16x8 __attribute__((ext_vector_type(8)));
typedef __bf16 bf16x4 __attribute__((ext_vector_type(4)));

__device__ __forceinline__ void load_to_lds16(const void* g, void* l) {
  auto gp = (const __attribute__((address_space(1))) void*)(reinterpret_cast<uintptr_t>(g));
  auto lp = (__attribute__((address_space(3))) void*)(reinterpret_cast<uintptr_t>(l));
  __builtin_amdgcn_global_load_lds(gp, lp, 16, 0, 0);
}

// ---- prep: fp32 -> bf16 + row norms + zero rowsum ------------------------
__global__ __launch_bounds__(256) void prep_kernel(const float* __restrict__ f,
                                                   __bf16* __restrict__ fbf,
                                                   float* __restrict__ sq,
                                                   float* __restrict__ rowsum) {
  const int t = threadIdx.x;
  if (t < 2) rowsum[blockIdx.x * 2 + t] = 0.f;
  const int row = blockIdx.x * 2 + (t >> 7);
  const int ci = (t & 127) * 4;
  const float4 v = *(const float4*)(f + (size_t)row * DIM + ci);
  bf16x4 b;
  b[0] = (__bf16)v.x; b[1] = (__bf16)v.y; b[2] = (__bf16)v.z; b[3] = (__bf16)v.w;
  *(bf16x4*)(fbf + (size_t)row * DIM + ci) = b;
  float s = v.x * v.x + v.y * v.y + v.z * v.z + v.w * v.w;
#pragma unroll
  for (int off = 1; off < 64; off <<= 1) s += __shfl_xor(s, off, 64);
  __shared__ float red[4];
  if ((t & 63) == 0) red[t >> 6] = s;
  __syncthreads();
  if ((t & 127) == 0) sq[row] = red[t >> 6] + red[(t >> 6) + 1];
}

// ---- fused GEMM (upper triangle, super-block XCD order) + Cauchy epilogue -
__global__ __launch_bounds__(256) void gemm_kernel(const __bf16* __restrict__ fbf,
                                                   const float* __restrict__ sq,
                                                   float* __restrict__ rowsum,
                                                   float* __restrict__ spart) {
  __shared__ __bf16 aT[128 * 32];  // [rowpair][8 x 16B chunks, XOR-swizzled]
  __shared__ __bf16 bT[128 * 32];

  // Super-block tile decode (see header comment). All-scalar, uniform.
  int by, bx;
  {
    const int x = blockIdx.x & 7;       // XCD
    const int k = blockIdx.x >> 3;      // 0..259 within XCD
    if (x < 6 && k < 256) {
      // off-diag super (sr,sc) for this XCD, row-major 16x16 tiles inside
      const int sr = (x <= 2) ? 0 : (x <= 4 ? 1 : 2);
      const int sc = (x == 0) ? 1 : (x == 1 ? 2 : (x == 2 ? 3 : (x == 3 ? 2 : 3)));
      by = sr * 16 + (k >> 4);
      bx = sc * 16 + (k & 15);
    } else {
      // diag enumeration g in [0,544): super d = g/136, then j-major triangle
      const int g = (x < 6) ? (520 + x * 4 + (k - 256)) : ((x - 6) * 260 + k);
      const int d = g / 136;
      int r = g - d * 136;              // r = j*(j+1)/2 + i, i<=j
      int j = 0;
      while (r >= j + 1) { r -= (j + 1); ++j; }
      by = d * 16 + r;                  // i
      bx = d * 16 + j;
    }
  }
  const int brow = by * 128;
  const int bcol = bx * 128;
  const bool diag = (by == bx);

  const int t = threadIdx.x;
  const int lane = t & 63;
  const int w = t >> 6;
  const int wrow = (w >> 1) * 64;
  const int wcol = (w & 1) * 64;
  const int q4 = lane >> 4;  // 0..3
  const int lc = lane & 15;  // 0..15

  floatx4 acc[4][4] = {};

  // staging lane -> (global row, 16B chunk) under XOR swizzle:
  // LDS slot (rp, u') holds global (row = rp*2 + (u>>2), chunk = u&3), u = u'^(rp&7)
  int grow[2], gofs[2];
#pragma unroll
  for (int it = 0; it < 2; ++it) {
    const int slot = it * 256 + t;
    const int rp = slot >> 3;
    const int u = (slot & 7) ^ (rp & 7);
    grow[it] = rp * 2 + (u >> 2);
    gofs[it] = (u & 3) * 8;
  }

  // fragment-read swizzle: u = (rr&1)*4+q4, u' = u ^ ((rr>>1)&7); rr = lc here.
  const int up = (((lc & 1) * 4) + q4) ^ (lc >> 1);
  const int rhalf = lc >> 1;

  for (int kt = 0; kt < DIM / 32; ++kt) {
    const int k0 = kt * 32;
#pragma unroll
    for (int it = 0; it < 2; ++it) {
      load_to_lds16(fbf + (size_t)(brow + grow[it]) * DIM + k0 + gofs[it],
                    &aT[t * 8 + it * 2048]);
      load_to_lds16(fbf + (size_t)(bcol + grow[it]) * DIM + k0 + gofs[it],
                    &bT[t * 8 + it * 2048]);
    }
    __syncthreads();
    bf16x8 af[4], bfr[4];
#pragma unroll
    for (int mr = 0; mr < 4; ++mr)
      af[mr] = *(const bf16x8*)&aT[((wrow >> 1) + mr * 8 + rhalf) * 64 + up * 8];
#pragma unroll
    for (int mc = 0; mc < 4; ++mc)
      bfr[mc] = *(const bf16x8*)&bT[((wcol >> 1) + mc * 8 + rhalf) * 64 + up * 8];
#pragma unroll
    for (int mr = 0; mr < 4; ++mr)
#pragma unroll
      for (int mc = 0; mc < 4; ++mc)
        acc[mr][mc] =
            __builtin_amdgcn_mfma_f32_16x16x32_bf16(af[mr], bfr[mc], acc[mr][mc], 0, 0, 0);
    __syncthreads();
  }

  // Epilogue. C/D layout: col = lane&15, row = (lane>>4)*4 + reg.
  float sqc[4];
#pragma unroll
  for (int mc = 0; mc < 4; ++mc) sqc[mc] = sq[bcol + wcol + mc * 16 + lc];

  float cs[4] = {0.f, 0.f, 0.f, 0.f};  // column partial sums (off-diag tiles)

#pragma unroll
  for (int mr = 0; mr < 4; ++mr) {
#pragma unroll
    for (int reg = 0; reg < 4; ++reg) {
      const int r = brow + wrow + mr * 16 + q4 * 4 + reg;
      const float sr = sq[r];
      const int pc = r ^ (N2 / 2);
      float rs = 0.f;
#pragma unroll
      for (int mc = 0; mc < 4; ++mc) {
        const int c = bcol + wcol + mc * 16 + lc;
        const float g = acc[mr][mc][reg];
        const float d2 = fmaxf(sr + sqc[mc] - 2.f * g, 0.f);
        const float s = T2 * __builtin_amdgcn_rcpf(d2 + T2);
        if (c != r) rs += s;  // diagonal excluded exactly (diag tiles only)
        cs[mc] += s;          // unused on diag tiles
        if (c == pc) { spart[r] = s; spart[pc] = s; }  // off-diag only, 1 lane
      }
#pragma unroll
      for (int off = 1; off < 16; off <<= 1) rs += __shfl_xor(rs, off, 64);
      if (lc == 0) atomicAdd(&rowsum[r], rs);
    }
  }

  if (!diag) {
#pragma unroll
    for (int mc = 0; mc < 4; ++mc) {
      float v = cs[mc];
      v += __shfl_xor(v, 16, 64);
      v += __shfl_xor(v, 32, 64);
      if (lane < 16) atomicAdd(&rowsum[bcol + wcol + mc * 16 + lane], v);
    }
  }
}

// ---- final scalar reduction ---------------------------------------------
__global__ __launch_bounds__(256) void final_kernel(const float* __restrict__ rowsum,
                                                    const float* __restrict__ spart,
                                                    float* __restrict__ out) {
  const int t = threadIdx.x;
  float a = 0.f;
  for (int r = t; r < N2; r += 256) a += logf(rowsum[r]) - logf(spart[r]);
#pragma unroll
  for (int off = 1; off < 64; off <<= 1) a += __shfl_xor(a, off, 64);
  __shared__ float red[4];
  if ((t & 63) == 0) red[t >> 6] = a;
  __syncthreads();
  if (t == 0) out[0] = (red[0] + red[1] + red[2] + red[3]) * (1.0f / (float)N2);
}

extern "C" void kernel_launch(void* const* d_in, const int* in_sizes, int n_in,
                              void* d_out, int out_size, void* d_ws, size_t ws_size,
                              hipStream_t stream) {
  const float* features = (const float*)d_in[0];
  float* out = (float*)d_out;

  char* ws = (char*)d_ws;
  __bf16* fbf = (__bf16*)ws;                                     // 8 MB
  float* sq = (float*)(ws + (size_t)N2 * DIM * sizeof(__bf16));  // 32 KB
  float* rowsum = sq + N2;                                       // 32 KB
  float* spart = rowsum + N2;                                    // 32 KB

  prep_kernel<<<N2 / 2, 256, 0, stream>>>(features, fbf, sq, rowsum);
  gemm_kernel<<<NTILES, 256, 0, stream>>>(fbf, sq, rowsum, spart);
  final_kernel<<<1, 256, 0, stream>>>(rowsum, spart, out);
}

// Round 3
// 141.684 us; speedup vs baseline: 1.2019x; 1.0718x over previous
//
#include <hip/hip_runtime.h>

// InfoCNECauchy: loss = mean_r log(sum_{j!=r} sim[r,j]) - mean_r log(sim[r, r^4096])
// sim = t^2/(d2+t^2), d2 = ||f_r||^2 + ||f_c||^2 - 2<f_r,f_c>, t=0.07
//
// R8: R5's proven gemm body + banded XCD map (72 us, best known), ONE change:
// BK 32 -> 64. R6/R7 post-mortems falsified all bandwidth theories (R7 cut
// L3 traffic, got slower; R6 cut panel bytes 2x, got slower). Revised model:
// latency-bound on the per-k-step __syncthreads vmcnt(0) drain (~80% stall,
// 16 drain windows/block, ~3 blocks/CU to cover them). BK=64 halves the drain
// count and doubles MFMA per window. LDS layout = two proven 8KB XOR-swizzled
// sub-regions per tile (identical math per region, 0 bank conflicts); ks=0/1
// processed sequentially so fragment regs don't grow (VGPR ~80, occupancy
// unchanged); LDS 32 KB -> still >=3 blocks/CU.

#define N2 8192
#define DIM 512
#define NT 64 /* 8192/128 tiles per dim */
#define NTILES (NT * (NT + 1) / 2)
#define T2 0.0049f

typedef float floatx4 __attribute__((ext_vector_type(4)));
typedef __bf16 bf16x8 __attribute__((ext_vector_type(8)));
typedef __bf16 bf16x4 __attribute__((ext_vector_type(4)));

__device__ __forceinline__ void load_to_lds16(const void* g, void* l) {
  auto gp = (const __attribute__((address_space(1))) void*)(reinterpret_cast<uintptr_t>(g));
  auto lp = (__attribute__((address_space(3))) void*)(reinterpret_cast<uintptr_t>(l));
  __builtin_amdgcn_global_load_lds(gp, lp, 16, 0, 0);
}

// ---- prep: fp32 -> bf16 + row norms + zero rowsum ------------------------
__global__ __launch_bounds__(256) void prep_kernel(const float* __restrict__ f,
                                                   __bf16* __restrict__ fbf,
                                                   float* __restrict__ sq,
                                                   float* __restrict__ rowsum) {
  const int t = threadIdx.x;
  if (t < 2) rowsum[blockIdx.x * 2 + t] = 0.f;
  const int row = blockIdx.x * 2 + (t >> 7);
  const int ci = (t & 127) * 4;
  const float4 v = *(const float4*)(f + (size_t)row * DIM + ci);
  bf16x4 b;
  b[0] = (__bf16)v.x; b[1] = (__bf16)v.y; b[2] = (__bf16)v.z; b[3] = (__bf16)v.w;
  *(bf16x4*)(fbf + (size_t)row * DIM + ci) = b;
  float s = v.x * v.x + v.y * v.y + v.z * v.z + v.w * v.w;
#pragma unroll
  for (int off = 1; off < 64; off <<= 1) s += __shfl_xor(s, off, 64);
  __shared__ float red[4];
  if ((t & 63) == 0) red[t >> 6] = s;
  __syncthreads();
  if ((t & 127) == 0) sq[row] = red[t >> 6] + red[(t >> 6) + 1];
}

// ---- fused GEMM (upper triangle, banded XCD order, BK=64) + epilogue -----
__global__ __launch_bounds__(256) void gemm_kernel(const __bf16* __restrict__ fbf,
                                                   const float* __restrict__ sq,
                                                   float* __restrict__ rowsum,
                                                   float* __restrict__ spart) {
  // two XOR-swizzled 8KB sub-regions (ks=0/1) per tensor
  __shared__ __bf16 aT[128 * 64];
  __shared__ __bf16 bT[128 * 64];

  // R5's banded tile decode (empirically best): XCD x owns row-bands
  // by in [4x,4x+4) and [60-4x,64-4x), bx-major, 260 tiles each.
  int by, bx;
  {
    const int x = blockIdx.x & 7;
    int kk = blockIdx.x >> 3;
    int band = x;
    const int n1 = 250 - 16 * x;
    if (kk >= n1) { kk -= n1; band = 15 - x; }
    const int by0 = band * 4;
    int bxx = by0;
    int cnt;
    while (kk >= (cnt = min(4, bxx - by0 + 1))) { kk -= cnt; ++bxx; }
    by = by0 + kk;
    bx = bxx;
  }
  const int brow = by * 128;
  const int bcol = bx * 128;
  const bool diag = (by == bx);

  const int t = threadIdx.x;
  const int lane = t & 63;
  const int w = t >> 6;
  const int wrow = (w >> 1) * 64;
  const int wcol = (w & 1) * 64;
  const int q4 = lane >> 4;  // 0..3
  const int lc = lane & 15;  // 0..15

  floatx4 acc[4][4] = {};

  // staging lane -> (global row, 16B chunk) under XOR swizzle (per sub-region):
  // LDS slot (rp, u') holds global (row = rp*2 + (u>>2), chunk = u&3), u = u'^(rp&7)
  int grow[2], gofs[2];
#pragma unroll
  for (int it = 0; it < 2; ++it) {
    const int slot = it * 256 + t;
    const int rp = slot >> 3;
    const int u = (slot & 7) ^ (rp & 7);
    grow[it] = rp * 2 + (u >> 2);
    gofs[it] = (u & 3) * 8;
  }

  // fragment-read swizzle: u = (rr&1)*4+q4, u' = u ^ ((rr>>1)&7); rr = lc here.
  const int up = (((lc & 1) * 4) + q4) ^ (lc >> 1);
  const int rhalf = lc >> 1;

  for (int kt = 0; kt < DIM / 64; ++kt) {
    const int k0 = kt * 64;
#pragma unroll
    for (int it = 0; it < 2; ++it) {
#pragma unroll
      for (int ks = 0; ks < 2; ++ks) {
        load_to_lds16(fbf + (size_t)(brow + grow[it]) * DIM + k0 + ks * 32 + gofs[it],
                      &aT[ks * 4096 + it * 2048 + t * 8]);
        load_to_lds16(fbf + (size_t)(bcol + grow[it]) * DIM + k0 + ks * 32 + gofs[it],
                      &bT[ks * 4096 + it * 2048 + t * 8]);
      }
    }
    __syncthreads();
#pragma unroll
    for (int ks = 0; ks < 2; ++ks) {
      bf16x8 af[4], bfr[4];
#pragma unroll
      for (int mr = 0; mr < 4; ++mr)
        af[mr] = *(const bf16x8*)&aT[ks * 4096 + ((wrow >> 1) + mr * 8 + rhalf) * 64 + up * 8];
#pragma unroll
      for (int mc = 0; mc < 4; ++mc)
        bfr[mc] = *(const bf16x8*)&bT[ks * 4096 + ((wcol >> 1) + mc * 8 + rhalf) * 64 + up * 8];
#pragma unroll
      for (int mr = 0; mr < 4; ++mr)
#pragma unroll
        for (int mc = 0; mc < 4; ++mc)
          acc[mr][mc] =
              __builtin_amdgcn_mfma_f32_16x16x32_bf16(af[mr], bfr[mc], acc[mr][mc], 0, 0, 0);
    }
    __syncthreads();
  }

  // Epilogue. C/D layout: col = lane&15, row = (lane>>4)*4 + reg.
  float sqc[4];
#pragma unroll
  for (int mc = 0; mc < 4; ++mc) sqc[mc] = sq[bcol + wcol + mc * 16 + lc];

  float cs[4] = {0.f, 0.f, 0.f, 0.f};  // column partial sums (off-diag tiles)

#pragma unroll
  for (int mr = 0; mr < 4; ++mr) {
#pragma unroll
    for (int reg = 0; reg < 4; ++reg) {
      const int r = brow + wrow + mr * 16 + q4 * 4 + reg;
      const float sr = sq[r];
      const int pc = r ^ (N2 / 2);
      float rs = 0.f;
#pragma unroll
      for (int mc = 0; mc < 4; ++mc) {
        const int c = bcol + wcol + mc * 16 + lc;
        const float g = acc[mr][mc][reg];
        const float d2 = fmaxf(sr + sqc[mc] - 2.f * g, 0.f);
        const float s = T2 * __builtin_amdgcn_rcpf(d2 + T2);
        if (c != r) rs += s;  // diagonal excluded exactly (diag tiles only)
        cs[mc] += s;          // unused on diag tiles
        if (c == pc) { spart[r] = s; spart[pc] = s; }  // off-diag only, 1 lane
      }
#pragma unroll
      for (int off = 1; off < 16; off <<= 1) rs += __shfl_xor(rs, off, 64);
      if (lc == 0) atomicAdd(&rowsum[r], rs);
    }
  }

  if (!diag) {
#pragma unroll
    for (int mc = 0; mc < 4; ++mc) {
      float v = cs[mc];
      v += __shfl_xor(v, 16, 64);
      v += __shfl_xor(v, 32, 64);
      if (lane < 16) atomicAdd(&rowsum[bcol + wcol + mc * 16 + lane], v);
    }
  }
}

// ---- final scalar reduction ---------------------------------------------
__global__ __launch_bounds__(256) void final_kernel(const float* __restrict__ rowsum,
                                                    const float* __restrict__ spart,
                                                    float* __restrict__ out) {
  const int t = threadIdx.x;
  float a = 0.f;
  for (int r = t; r < N2; r += 256) a += logf(rowsum[r]) - logf(spart[r]);
#pragma unroll
  for (int off = 1; off < 64; off <<= 1) a += __shfl_xor(a, off, 64);
  __shared__ float red[4];
  if ((t & 63) == 0) red[t >> 6] = a;
  __syncthreads();
  if (t == 0) out[0] = (red[0] + red[1] + red[2] + red[3]) * (1.0f / (float)N2);
}

extern "C" void kernel_launch(void* const* d_in, const int* in_sizes, int n_in,
                              void* d_out, int out_size, void* d_ws, size_t ws_size,
                              hipStream_t stream) {
  const float* features = (const float*)d_in[0];
  float* out = (float*)d_out;

  char* ws = (char*)d_ws;
  __bf16* fbf = (__bf16*)ws;                                     // 8 MB
  float* sq = (float*)(ws + (size_t)N2 * DIM * sizeof(__bf16));  // 32 KB
  float* rowsum = sq + N2;                                       // 32 KB
  float* spart = rowsum + N2;                                    // 32 KB

  prep_kernel<<<N2 / 2, 256, 0, stream>>>(features, fbf, sq, rowsum);
  gemm_kernel<<<NTILES, 256, 0, stream>>>(fbf, sq, rowsum, spart);
  final_kernel<<<1, 256, 0, stream>>>(rowsum, spart, out);
}